// Round 2
// baseline (5135.648 us; speedup 1.0000x reference)
//
#include <hip/hip_runtime.h>
#include <hip/hip_bf16.h>

#define N_NODES_C 100000
#define N_EDGES_C 1600000
#define FEATS 128

// ---------------------------------------------------------------------------
// dtype-adaptive load/store helpers. bf: 1 = bf16, 0 = fp32.
__device__ inline float load1v(const void* p, size_t i, int bf) {
    return bf ? __bfloat162float(((const __hip_bfloat16*)p)[i])
              : ((const float*)p)[i];
}
__device__ inline float2 load2v(const void* p, size_t i, int bf) {
    if (bf) {
        __hip_bfloat162 h = *(const __hip_bfloat162*)((const __hip_bfloat16*)p + i);
        return __bfloat1622float2(h);
    }
    return *(const float2*)((const float*)p + i);
}
__device__ inline void store1v(void* p, size_t i, int bf, float v) {
    if (bf) ((__hip_bfloat16*)p)[i] = __float2bfloat16(v);
    else    ((float*)p)[i] = v;
}

// ---------------------------------------------------------------------------
// Probe the features buffer: genuine bf16 ~N(0,1) data has exponent <= ~0x81;
// fp32 data read as bf16 has mantissa-junk halves with exponent >= 0xC0 (~25%
// of elements). gflag = 1 iff float tensors are bf16.
__global__ void detect_kernel(const void* __restrict__ feats, int* __restrict__ gflag) {
    const unsigned short* u = (const unsigned short*)feats;
    int bad = 0;
    for (int i = threadIdx.x; i < 2048; i += 64) {
        unsigned e = (u[i] >> 7) & 0xFF;          // bf16 exponent field
        if (e >= 0xC0) bad++;                     // |x| >= 2^65: impossible for real data
    }
#pragma unroll
    for (int off = 32; off > 0; off >>= 1) bad += __shfl_down(bad, off, 64);
    if (threadIdx.x == 0) *gflag = (bad == 0) ? 1 : 0;
}

// ---------------------------------------------------------------------------
__global__ void deg_kernel(const int* __restrict__ dst, unsigned* __restrict__ deg,
                           int n_edges) {
    int e = blockIdx.x * blockDim.x + threadIdx.x;
    if (e < n_edges) atomicAdd(&deg[dst[e]], 1u);
}

// ---------------------------------------------------------------------------
// agg[dst] += h[src]. One 64-lane wave per edge, 2 feats/lane, fp32 atomics.
// h_mode: 0 = fp32, 1 = bf16, 2 = use *gflag.
__global__ void scatter_kernel(const void* __restrict__ h,
                               const int* __restrict__ src,
                               const int* __restrict__ dst,
                               float* __restrict__ agg,
                               const int* __restrict__ gflag,
                               int h_mode, int n_edges) {
    long t = (long)blockIdx.x * blockDim.x + threadIdx.x;
    int e    = (int)(t >> 6);
    int lane = (int)(t & 63);
    if (e >= n_edges) return;
    int bf = (h_mode == 2) ? *gflag : h_mode;
    int s = src[e];
    int d = dst[e];
    float2 f = load2v(h, (size_t)s * FEATS + lane * 2, bf);
    float* ap = agg + (size_t)d * FEATS + lane * 2;
    unsafeAtomicAdd(ap,     f.x);
    unsafeAtomicAdd(ap + 1, f.y);
}

// ---------------------------------------------------------------------------
// out[n,:] = h[n,:]@Ws + bs + (agg[n,:]/max(deg,1))@Wn + bn (+relu +L2norm).
// One block per node; thread j computes output feature j.
// h_mode/out_mode: 0 = fp32, 1 = bf16, 2 = use *gflag. Weights always *gflag.
template <int OUT, bool ACTNORM>
__global__ void sage_linear(const void* __restrict__ h,
                            const float* __restrict__ agg,
                            const unsigned* __restrict__ deg,
                            const void* __restrict__ Ws, const void* __restrict__ bs,
                            const void* __restrict__ Wn, const void* __restrict__ bn,
                            void* __restrict__ out,
                            const int* __restrict__ gflag,
                            int h_mode, int out_mode) {
    int n   = blockIdx.x;
    int tid = threadIdx.x;
    __shared__ float hs[FEATS];
    __shared__ float hn[FEATS];
    __shared__ float wsum[2];

    int gb  = *gflag;
    int hbf = (h_mode  == 2) ? gb : h_mode;
    int obf = (out_mode == 2) ? gb : out_mode;

    float invdeg = 1.0f / fmaxf((float)deg[n], 1.0f);
    for (int k = tid; k < FEATS; k += blockDim.x) {
        hs[k] = load1v(h, (size_t)n * FEATS + k, hbf);
        hn[k] = agg[(size_t)n * FEATS + k] * invdeg;
    }
    __syncthreads();

    int j = tid;
    float r = 0.0f;
    if (j < OUT) {
        float acc = load1v(bs, j, gb) + load1v(bn, j, gb);
        if (gb) {
            const __hip_bfloat16* ws16 = (const __hip_bfloat16*)Ws;
            const __hip_bfloat16* wn16 = (const __hip_bfloat16*)Wn;
#pragma unroll 8
            for (int k = 0; k < FEATS; ++k) {
                acc += hs[k] * __bfloat162float(ws16[k * OUT + j]);
                acc += hn[k] * __bfloat162float(wn16[k * OUT + j]);
            }
        } else {
            const float* wsf = (const float*)Ws;
            const float* wnf = (const float*)Wn;
#pragma unroll 8
            for (int k = 0; k < FEATS; ++k) {
                acc += hs[k] * wsf[k * OUT + j];
                acc += hn[k] * wnf[k * OUT + j];
            }
        }
        r = acc;
    }

    if (ACTNORM) {
        r = fmaxf(r, 0.0f);                       // relu BEFORE norm (matches ref)
        float v = r * r;
#pragma unroll
        for (int off = 32; off > 0; off >>= 1) v += __shfl_down(v, off, 64);
        if ((tid & 63) == 0) wsum[tid >> 6] = v;
        __syncthreads();
        float total = wsum[0] + (blockDim.x > 64 ? wsum[1] : 0.0f);
        float scale = 1.0f / fmaxf(sqrtf(total), 1e-12f);
        if (j < OUT) store1v(out, (size_t)n * OUT + j, obf, r * scale);
    } else {
        if (j < OUT) store1v(out, (size_t)n * OUT + j, obf, r);
    }
}

// ---------------------------------------------------------------------------
extern "C" void kernel_launch(void* const* d_in, const int* in_sizes, int n_in,
                              void* d_out, int out_size, void* d_ws, size_t ws_size,
                              hipStream_t stream) {
    const void* feats = d_in[0];
    const int*  src   = (const int*)d_in[1];
    const int*  dst   = (const int*)d_in[2];

    char* ws = (char*)d_ws;
    const size_t H32  = (size_t)N_NODES_C * FEATS * sizeof(float);   // 51,200,000 B
    const size_t H16  = H32 / 2;
    const size_t DEGB = (size_t)N_NODES_C * sizeof(unsigned);

    // intermediates fp32 if workspace allows (accuracy), else bf16
    int    ibf = (ws_size >= 3 * H32 + DEGB + 64) ? 0 : 1;
    size_t Hsz = ibf ? H16 : H32;

    float*    agg   = (float*)ws;
    void*     h1    = ws + H32;
    void*     h2    = ws + H32 + Hsz;
    unsigned* deg   = (unsigned*)(ws + H32 + 2 * Hsz);
    int*      gflag = (int*)(ws + H32 + 2 * Hsz + DEGB);

    detect_kernel<<<1, 64, 0, stream>>>(feats, gflag);

    hipMemsetAsync(deg, 0, DEGB, stream);
    deg_kernel<<<(N_EDGES_C + 255) / 256, 256, 0, stream>>>(dst, deg, N_EDGES_C);

    const int sblk = (int)(((long)N_EDGES_C * 64) / 256);            // 400,000

    // layer 0: feats -> h1 (relu + norm)
    hipMemsetAsync(agg, 0, H32, stream);
    scatter_kernel<<<sblk, 256, 0, stream>>>(feats, src, dst, agg, gflag, 2, N_EDGES_C);
    sage_linear<128, true><<<N_NODES_C, 128, 0, stream>>>(
        feats, agg, deg, d_in[3], d_in[4], d_in[5], d_in[6], h1, gflag, 2, ibf);

    // layer 1: h1 -> h2 (relu + norm)
    hipMemsetAsync(agg, 0, H32, stream);
    scatter_kernel<<<sblk, 256, 0, stream>>>(h1, src, dst, agg, gflag, ibf, N_EDGES_C);
    sage_linear<128, true><<<N_NODES_C, 128, 0, stream>>>(
        h1, agg, deg, d_in[7], d_in[8], d_in[9], d_in[10], h2, gflag, ibf, ibf);

    // layer 2: h2 -> out (no act/norm, 40 classes), out dtype = input float dtype
    hipMemsetAsync(agg, 0, H32, stream);
    scatter_kernel<<<sblk, 256, 0, stream>>>(h2, src, dst, agg, gflag, ibf, N_EDGES_C);
    sage_linear<40, false><<<N_NODES_C, 64, 0, stream>>>(
        h2, agg, deg, d_in[11], d_in[12], d_in[13], d_in[14], d_out, gflag, ibf, 2);
}

// Round 3
// 1773.680 us; speedup vs baseline: 2.8955x; 2.8955x over previous
//
#include <hip/hip_runtime.h>
#include <hip/hip_bf16.h>

#define N_NODES_C 100000
#define N_EDGES_C 1600000
#define FEATS 128
#define SCAN_B 256
#define N_BLKS ((N_NODES_C + SCAN_B - 1) / SCAN_B)   // 391

// ---------------------------------------------------------------------------
// dtype-adaptive load/store helpers. bf: 1 = bf16, 0 = fp32.
__device__ inline float load1v(const void* p, size_t i, int bf) {
    return bf ? __bfloat162float(((const __hip_bfloat16*)p)[i])
              : ((const float*)p)[i];
}
__device__ inline float2 load2v(const void* p, size_t i, int bf) {
    if (bf) {
        __hip_bfloat162 h = *(const __hip_bfloat162*)((const __hip_bfloat16*)p + i);
        return __bfloat1622float2(h);
    }
    return *(const float2*)((const float*)p + i);
}
__device__ inline void store1v(void* p, size_t i, int bf, float v) {
    if (bf) ((__hip_bfloat16*)p)[i] = __float2bfloat16(v);
    else    ((float*)p)[i] = v;
}

// ---------------------------------------------------------------------------
// Probe features buffer dtype: bf16 data has sane exponents; fp32 read as bf16
// shows junk exponents >= 0xC0 in ~25% of halves. gflag = 1 iff bf16.
__global__ void detect_kernel(const void* __restrict__ feats, int* __restrict__ gflag) {
    const unsigned short* u = (const unsigned short*)feats;
    int bad = 0;
    for (int i = threadIdx.x; i < 2048; i += 64) {
        unsigned e = (u[i] >> 7) & 0xFF;
        if (e >= 0xC0) bad++;
    }
#pragma unroll
    for (int off = 32; off > 0; off >>= 1) bad += __shfl_down(bad, off, 64);
    if (threadIdx.x == 0) *gflag = (bad == 0) ? 1 : 0;
}

// ---------------------------------------------------------------------------
// CSR build step 1: deg[i] = #edges with dst == i
__global__ void deg_kernel(const int* __restrict__ dst, int* __restrict__ deg,
                           int n_edges) {
    int e = blockIdx.x * blockDim.x + threadIdx.x;
    if (e < n_edges) atomicAdd(&deg[dst[e]], 1);
}

// CSR build step 2a: per-256-node block sums
__global__ void scan1_kernel(const int* __restrict__ deg, int* __restrict__ blocksum) {
    __shared__ int ws[4];
    int i = blockIdx.x * SCAN_B + threadIdx.x;
    int v = (i < N_NODES_C) ? deg[i] : 0;
#pragma unroll
    for (int off = 32; off > 0; off >>= 1) v += __shfl_down(v, off, 64);
    if ((threadIdx.x & 63) == 0) ws[threadIdx.x >> 6] = v;
    __syncthreads();
    if (threadIdx.x == 0) blocksum[blockIdx.x] = ws[0] + ws[1] + ws[2] + ws[3];
}

// CSR build step 2b: exclusive scan of 391 block sums (single block)
__global__ void scan2_kernel(int* __restrict__ blocksum) {
    __shared__ int buf[N_BLKS];
    for (int i = threadIdx.x; i < N_BLKS; i += 64) buf[i] = blocksum[i];
    __syncthreads();
    if (threadIdx.x == 0) {
        int run = 0;
        for (int b = 0; b < N_BLKS; ++b) { int t = buf[b]; buf[b] = run; run += t; }
    }
    __syncthreads();
    for (int i = threadIdx.x; i < N_BLKS; i += 64) blocksum[i] = buf[i];
}

// CSR build step 2c: per-node exclusive row offsets (+ cursor copy)
__global__ void scan3_kernel(const int* __restrict__ deg, const int* __restrict__ blockoff,
                             int* __restrict__ row_start, int* __restrict__ cursor) {
    __shared__ int sd[SCAN_B];
    int tid = threadIdx.x;
    int i = blockIdx.x * SCAN_B + tid;
    int v = (i < N_NODES_C) ? deg[i] : 0;
    sd[tid] = v;
    __syncthreads();
#pragma unroll
    for (int st = 1; st < SCAN_B; st <<= 1) {
        int t = (tid >= st) ? sd[tid - st] : 0;
        __syncthreads();
        sd[tid] += t;
        __syncthreads();
    }
    if (i < N_NODES_C) {
        int excl = sd[tid] - v + blockoff[blockIdx.x];
        row_start[i] = excl;
        cursor[i]    = excl;
    }
}

// CSR build step 3: fill neighbor lists
__global__ void csr_fill_kernel(const int* __restrict__ src, const int* __restrict__ dst,
                                int* __restrict__ cursor, int* __restrict__ csr,
                                int n_edges) {
    int e = blockIdx.x * blockDim.x + threadIdx.x;
    if (e < n_edges) {
        int pos = atomicAdd(&cursor[dst[e]], 1);
        csr[pos] = src[e];
    }
}

// ---------------------------------------------------------------------------
// Gather-mean aggregation: one wave per node, lane covers 2 feats.
// Writes MEAN directly into agg (fp32). No atomics, no memset needed.
__global__ void gather_kernel(const void* __restrict__ h,
                              const int* __restrict__ csr,
                              const int* __restrict__ row_start,
                              const int* __restrict__ deg,
                              float* __restrict__ agg,
                              const int* __restrict__ gflag, int h_mode) {
    int node = blockIdx.x * 4 + (threadIdx.x >> 6);
    int lane = threadIdx.x & 63;
    if (node >= N_NODES_C) return;
    int bf = (h_mode == 2) ? *gflag : h_mode;
    int start = row_start[node];
    int d     = deg[node];
    float ax = 0.0f, ay = 0.0f;
    for (int i = 0; i < d; ++i) {
        int s = __builtin_amdgcn_readfirstlane(csr[start + i]);
        float2 f = load2v(h, (size_t)s * FEATS + lane * 2, bf);
        ax += f.x; ay += f.y;
    }
    float inv = 1.0f / fmaxf((float)d, 1.0f);
    float* ap = agg + (size_t)node * FEATS + lane * 2;
    ap[0] = ax * inv;
    ap[1] = ay * inv;
}

// ---------------------------------------------------------------------------
// out[n,:] = h[n,:]@Ws + bs + agg[n,:]@Wn + bn (+relu +L2norm). agg is mean.
// One block per node; thread j computes output feature j.
template <int OUT, bool ACTNORM>
__global__ void sage_linear(const void* __restrict__ h,
                            const float* __restrict__ agg,
                            const void* __restrict__ Ws, const void* __restrict__ bs,
                            const void* __restrict__ Wn, const void* __restrict__ bn,
                            void* __restrict__ out,
                            const int* __restrict__ gflag,
                            int h_mode, int out_mode) {
    int n   = blockIdx.x;
    int tid = threadIdx.x;
    __shared__ float hs[FEATS];
    __shared__ float hn[FEATS];
    __shared__ float wsum[2];

    int gb  = *gflag;
    int hbf = (h_mode  == 2) ? gb : h_mode;
    int obf = (out_mode == 2) ? gb : out_mode;

    for (int k = tid; k < FEATS; k += blockDim.x) {
        hs[k] = load1v(h, (size_t)n * FEATS + k, hbf);
        hn[k] = agg[(size_t)n * FEATS + k];
    }
    __syncthreads();

    int j = tid;
    float r = 0.0f;
    if (j < OUT) {
        float acc = load1v(bs, j, gb) + load1v(bn, j, gb);
        if (gb) {
            const __hip_bfloat16* ws16 = (const __hip_bfloat16*)Ws;
            const __hip_bfloat16* wn16 = (const __hip_bfloat16*)Wn;
#pragma unroll 8
            for (int k = 0; k < FEATS; ++k) {
                acc += hs[k] * __bfloat162float(ws16[k * OUT + j]);
                acc += hn[k] * __bfloat162float(wn16[k * OUT + j]);
            }
        } else {
            const float* wsf = (const float*)Ws;
            const float* wnf = (const float*)Wn;
#pragma unroll 8
            for (int k = 0; k < FEATS; ++k) {
                acc += hs[k] * wsf[k * OUT + j];
                acc += hn[k] * wnf[k * OUT + j];
            }
        }
        r = acc;
    }

    if (ACTNORM) {
        r = fmaxf(r, 0.0f);
        float v = r * r;
#pragma unroll
        for (int off = 32; off > 0; off >>= 1) v += __shfl_down(v, off, 64);
        if ((tid & 63) == 0) wsum[tid >> 6] = v;
        __syncthreads();
        float total = wsum[0] + (blockDim.x > 64 ? wsum[1] : 0.0f);
        float scale = 1.0f / fmaxf(sqrtf(total), 1e-12f);
        if (j < OUT) store1v(out, (size_t)n * OUT + j, obf, r * scale);
    } else {
        if (j < OUT) store1v(out, (size_t)n * OUT + j, obf, r);
    }
}

// ---------------------------------------------------------------------------
extern "C" void kernel_launch(void* const* d_in, const int* in_sizes, int n_in,
                              void* d_out, int out_size, void* d_ws, size_t ws_size,
                              hipStream_t stream) {
    const void* feats = d_in[0];
    const int*  src   = (const int*)d_in[1];
    const int*  dst   = (const int*)d_in[2];

    char* ws = (char*)d_ws;
    const size_t H32  = (size_t)N_NODES_C * FEATS * sizeof(float);   // 51,200,000 B
    const size_t H16  = H32 / 2;
    const size_t NI   = (size_t)N_NODES_C * sizeof(int);             //    400,000 B
    const size_t EI   = (size_t)N_EDGES_C * sizeof(int);             //  6,400,000 B
    const size_t MISC = 4 * NI + EI + 4096;                          // deg,row,cur,bsum,csr,gflag

    // intermediates fp32 if workspace allows, else bf16
    int    ibf = (ws_size >= 3 * H32 + MISC) ? 0 : 1;
    size_t Hsz = ibf ? H16 : H32;

    float* agg       = (float*)ws;
    void*  h1        = ws + H32;
    void*  h2        = ws + H32 + Hsz;
    char*  p         = ws + H32 + 2 * Hsz;
    int*   deg       = (int*)p;            p += NI;
    int*   row_start = (int*)p;            p += NI;
    int*   cursor    = (int*)p;            p += NI;
    int*   csr       = (int*)p;            p += EI;
    int*   blocksum  = (int*)p;            p += ((N_BLKS * 4 + 255) / 256) * 256;
    int*   gflag     = (int*)p;

    detect_kernel<<<1, 64, 0, stream>>>(feats, gflag);

    // ---- CSR build (per call; ws is re-poisoned before every launch) ----
    hipMemsetAsync(deg, 0, NI, stream);
    deg_kernel<<<(N_EDGES_C + 255) / 256, 256, 0, stream>>>(dst, deg, N_EDGES_C);
    scan1_kernel<<<N_BLKS, SCAN_B, 0, stream>>>(deg, blocksum);
    scan2_kernel<<<1, 64, 0, stream>>>(blocksum);
    scan3_kernel<<<N_BLKS, SCAN_B, 0, stream>>>(deg, blocksum, row_start, cursor);
    csr_fill_kernel<<<(N_EDGES_C + 255) / 256, 256, 0, stream>>>(src, dst, cursor, csr, N_EDGES_C);

    const int gblk = (N_NODES_C + 3) / 4;   // 4 nodes (waves) per 256-thread block

    // layer 0: feats -> h1 (relu + norm)
    gather_kernel<<<gblk, 256, 0, stream>>>(feats, csr, row_start, deg, agg, gflag, 2);
    sage_linear<128, true><<<N_NODES_C, 128, 0, stream>>>(
        feats, agg, d_in[3], d_in[4], d_in[5], d_in[6], h1, gflag, 2, ibf);

    // layer 1: h1 -> h2 (relu + norm)
    gather_kernel<<<gblk, 256, 0, stream>>>(h1, csr, row_start, deg, agg, gflag, ibf);
    sage_linear<128, true><<<N_NODES_C, 128, 0, stream>>>(
        h1, agg, d_in[7], d_in[8], d_in[9], d_in[10], h2, gflag, ibf, ibf);

    // layer 2: h2 -> out (no act/norm, 40 classes)
    gather_kernel<<<gblk, 256, 0, stream>>>(h2, csr, row_start, deg, agg, gflag, ibf);
    sage_linear<40, false><<<N_NODES_C, 64, 0, stream>>>(
        h2, agg, d_in[11], d_in[12], d_in[13], d_in[14], d_out, gflag, ibf, 2);
}

// Round 4
// 649.128 us; speedup vs baseline: 7.9116x; 2.7324x over previous
//
#include <hip/hip_runtime.h>
#include <hip/hip_bf16.h>

#define N_NODES_C 100000
#define N_EDGES_C 1600000
#define SCAN_B 256
#define N_BLKS ((N_NODES_C + SCAN_B - 1) / SCAN_B)   // 391

typedef __attribute__((ext_vector_type(8))) short          short8;   // 8 bf16
typedef __attribute__((ext_vector_type(4))) float          f32x4;
typedef __attribute__((ext_vector_type(4))) unsigned int   u32x4;
typedef __attribute__((ext_vector_type(4))) unsigned short u16x4;

// ---------------------------------------------------------------------------
__device__ inline float load1v(const void* p, size_t i, int bf) {
    return bf ? __bfloat162float(((const __hip_bfloat16*)p)[i])
              : ((const float*)p)[i];
}
__device__ inline unsigned short f2bf(float f) {
    __hip_bfloat16 h = __float2bfloat16(f);
    return *reinterpret_cast<unsigned short*>(&h);
}
__device__ inline float bf_lo(unsigned u) { return __uint_as_float(u << 16); }
__device__ inline float bf_hi(unsigned u) { return __uint_as_float(u & 0xffff0000u); }

// ---------------------------------------------------------------------------
// Dtype probe: fp32 read as bf16 shows junk exponents >= 0xC0. gflag=1 iff bf16.
__global__ void detect_kernel(const void* __restrict__ feats, int* __restrict__ gflag) {
    const unsigned short* u = (const unsigned short*)feats;
    int bad = 0;
    for (int i = threadIdx.x; i < 2048; i += 64) {
        unsigned e = (u[i] >> 7) & 0xFF;
        if (e >= 0xC0) bad++;
    }
#pragma unroll
    for (int off = 32; off > 0; off >>= 1) bad += __shfl_down(bad, off, 64);
    if (threadIdx.x == 0) *gflag = (bad == 0) ? 1 : 0;
}

// ---------------------------------------------------------------------------
// CSR build (unchanged from round 3 — verified)
__global__ void deg_kernel(const int* __restrict__ dst, int* __restrict__ deg, int n_edges) {
    int e = blockIdx.x * blockDim.x + threadIdx.x;
    if (e < n_edges) atomicAdd(&deg[dst[e]], 1);
}
__global__ void scan1_kernel(const int* __restrict__ deg, int* __restrict__ blocksum) {
    __shared__ int ws[4];
    int i = blockIdx.x * SCAN_B + threadIdx.x;
    int v = (i < N_NODES_C) ? deg[i] : 0;
#pragma unroll
    for (int off = 32; off > 0; off >>= 1) v += __shfl_down(v, off, 64);
    if ((threadIdx.x & 63) == 0) ws[threadIdx.x >> 6] = v;
    __syncthreads();
    if (threadIdx.x == 0) blocksum[blockIdx.x] = ws[0] + ws[1] + ws[2] + ws[3];
}
__global__ void scan2_kernel(int* __restrict__ blocksum) {
    __shared__ int buf[N_BLKS];
    for (int i = threadIdx.x; i < N_BLKS; i += 64) buf[i] = blocksum[i];
    __syncthreads();
    if (threadIdx.x == 0) {
        int run = 0;
        for (int b = 0; b < N_BLKS; ++b) { int t = buf[b]; buf[b] = run; run += t; }
    }
    __syncthreads();
    for (int i = threadIdx.x; i < N_BLKS; i += 64) blocksum[i] = buf[i];
}
__global__ void scan3_kernel(const int* __restrict__ deg, const int* __restrict__ blockoff,
                             int* __restrict__ row_start, int* __restrict__ cursor) {
    __shared__ int sd[SCAN_B];
    int tid = threadIdx.x;
    int i = blockIdx.x * SCAN_B + tid;
    int v = (i < N_NODES_C) ? deg[i] : 0;
    sd[tid] = v;
    __syncthreads();
#pragma unroll
    for (int st = 1; st < SCAN_B; st <<= 1) {
        int t = (tid >= st) ? sd[tid - st] : 0;
        __syncthreads();
        sd[tid] += t;
        __syncthreads();
    }
    if (i < N_NODES_C) {
        int excl = sd[tid] - v + blockoff[blockIdx.x];
        row_start[i] = excl;
        cursor[i]    = excl;
    }
}
__global__ void csr_fill_kernel(const int* __restrict__ src, const int* __restrict__ dst,
                                int* __restrict__ cursor, int* __restrict__ csr, int n_edges) {
    int e = blockIdx.x * blockDim.x + threadIdx.x;
    if (e < n_edges) {
        int pos = atomicAdd(&cursor[dst[e]], 1);
        csr[pos] = src[e];
    }
}

// ---------------------------------------------------------------------------
// Weight prep: Wt[n][k] (bf16, k=0..255; k<128 from W_self, else W_neigh),
// n = 0..127 (L0), 128..255 (L1), 256..303 (L2 padded to 48). bcat = bs+bn fp32.
__global__ void prep_weights(const void* Ws0, const void* bs0, const void* Wn0, const void* bn0,
                             const void* Ws1, const void* bs1, const void* Wn1, const void* bn1,
                             const void* Ws2, const void* bs2, const void* Wn2, const void* bn2,
                             unsigned short* __restrict__ Wt, float* __restrict__ bcat,
                             const int* __restrict__ gflag) {
    int gb = *gflag;
    int n = blockIdx.x;        // 0..303
    int k = threadIdx.x;       // 0..255
    const void *Wsl, *Wnl, *bsl, *bnl; int OUT, ncol;
    if (n < 128)      { Wsl=Ws0; Wnl=Wn0; bsl=bs0; bnl=bn0; OUT=128; ncol=n; }
    else if (n < 256) { Wsl=Ws1; Wnl=Wn1; bsl=bs1; bnl=bn1; OUT=128; ncol=n-128; }
    else              { Wsl=Ws2; Wnl=Wn2; bsl=bs2; bnl=bn2; OUT=40;  ncol=n-256; }
    float v = 0.0f;
    if (ncol < OUT)
        v = (k < 128) ? load1v(Wsl, (size_t)k * OUT + ncol, gb)
                      : load1v(Wnl, (size_t)(k - 128) * OUT + ncol, gb);
    Wt[(size_t)n * 256 + k] = f2bf(v);
    if (k == 0)
        bcat[n] = (ncol < OUT) ? load1v(bsl, ncol, gb) + load1v(bnl, ncol, gb) : 0.0f;
}

// ---------------------------------------------------------------------------
// Gather-mean into X[:,128:256] (bf16). One wave per node.
// bf16 src: 16 lanes/row (16 B each) -> 4 neighbors per iteration.
// fp32 src: 32 lanes/row -> 2 neighbors per iteration.
// copy_self: also write X[:,0:128] = src row (layer 0 only).
__global__ void gather_kernel(const void* __restrict__ hsrc, int src_stride,
                              int src_mode, int copy_self,
                              const int* __restrict__ csr,
                              const int* __restrict__ row_start,
                              const int* __restrict__ deg,
                              unsigned short* __restrict__ X,
                              const int* __restrict__ gflag) {
    int node = blockIdx.x * 4 + (threadIdx.x >> 6);
    if (node >= N_NODES_C) return;
    int lane = threadIdx.x & 63;
    int bf = (src_mode == 2) ? *gflag : src_mode;
    int start = row_start[node];
    int d = deg[node];
    const int* cp = csr + start;
    float inv = (d > 0) ? 1.0f / (float)d : 0.0f;

    if (bf) {
        int g = lane >> 4, sub = lane & 15;
        float a[8] = {0,0,0,0,0,0,0,0};
        const unsigned short* hb = (const unsigned short*)hsrc;
        int nfull = d >> 2, rem = d & 3;
        for (int i = 0; i < nfull; ++i) {
            int nb = cp[i * 4 + g];
            u32x4 raw = *(const u32x4*)(hb + (size_t)nb * src_stride + sub * 8);
            a[0] += bf_lo(raw.x); a[1] += bf_hi(raw.x);
            a[2] += bf_lo(raw.y); a[3] += bf_hi(raw.y);
            a[4] += bf_lo(raw.z); a[5] += bf_hi(raw.z);
            a[6] += bf_lo(raw.w); a[7] += bf_hi(raw.w);
        }
        if (g < rem) {
            int nb = cp[nfull * 4 + g];
            u32x4 raw = *(const u32x4*)(hb + (size_t)nb * src_stride + sub * 8);
            a[0] += bf_lo(raw.x); a[1] += bf_hi(raw.x);
            a[2] += bf_lo(raw.y); a[3] += bf_hi(raw.y);
            a[4] += bf_lo(raw.z); a[5] += bf_hi(raw.z);
            a[6] += bf_lo(raw.w); a[7] += bf_hi(raw.w);
        }
#pragma unroll
        for (int j = 0; j < 8; ++j) {
            a[j] += __shfl_xor(a[j], 16, 64);
            a[j] += __shfl_xor(a[j], 32, 64);
        }
        if (g == 0) {
            u32x4 o;
            o.x = (unsigned)f2bf(a[0] * inv) | ((unsigned)f2bf(a[1] * inv) << 16);
            o.y = (unsigned)f2bf(a[2] * inv) | ((unsigned)f2bf(a[3] * inv) << 16);
            o.z = (unsigned)f2bf(a[4] * inv) | ((unsigned)f2bf(a[5] * inv) << 16);
            o.w = (unsigned)f2bf(a[6] * inv) | ((unsigned)f2bf(a[7] * inv) << 16);
            *(u32x4*)(X + (size_t)node * 256 + 128 + sub * 8) = o;
        }
        if (copy_self && g == 1) {
            u32x4 raw = *(const u32x4*)(hb + (size_t)node * src_stride + sub * 8);
            *(u32x4*)(X + (size_t)node * 256 + sub * 8) = raw;
        }
    } else {
        int g = lane >> 5, sub = lane & 31;
        float a[4] = {0,0,0,0};
        const float* hf = (const float*)hsrc;
        int nfull = d >> 1, rem = d & 1;
        for (int i = 0; i < nfull; ++i) {
            int nb = cp[i * 2 + g];
            f32x4 raw = *(const f32x4*)(hf + (size_t)nb * src_stride + sub * 4);
            a[0] += raw.x; a[1] += raw.y; a[2] += raw.z; a[3] += raw.w;
        }
        if (g < rem) {
            int nb = cp[nfull * 2 + g];
            f32x4 raw = *(const f32x4*)(hf + (size_t)nb * src_stride + sub * 4);
            a[0] += raw.x; a[1] += raw.y; a[2] += raw.z; a[3] += raw.w;
        }
#pragma unroll
        for (int j = 0; j < 4; ++j) a[j] += __shfl_xor(a[j], 32, 64);
        if (g == 0) {
            u16x4 o = { f2bf(a[0] * inv), f2bf(a[1] * inv), f2bf(a[2] * inv), f2bf(a[3] * inv) };
            *(u16x4*)(X + (size_t)node * 256 + 128 + sub * 4) = o;
        }
        if (copy_self && g == 1) {
            f32x4 raw = *(const f32x4*)(hf + (size_t)node * src_stride + sub * 4);
            u16x4 o = { f2bf(raw.x), f2bf(raw.y), f2bf(raw.z), f2bf(raw.w) };
            *(u16x4*)(X + (size_t)node * 256 + sub * 4) = o;
        }
    }
}

// ---------------------------------------------------------------------------
// MFMA GEMM: C[node][n] = X[node][0:256] . Wt[n][0:256] + bias[n] (+relu+norm).
// Block: 256 thr = 4 waves, 64 nodes/block, wave w -> nodes w*16..w*16+15.
// W resident in LDS (xor-swizzled 16B chunks, conflict-free).
// mfma(bv, av): D col(lane&15)=node, row(quad*4+reg)=4 consecutive out cols.
template <int NCT, bool ACTNORM>
__global__ __launch_bounds__(256) void mfma_gemm(
        const unsigned short* __restrict__ X,   // [n][256] bf16
        const u32x4* __restrict__ Wg,           // [NCT*16][32] 16B chunks
        const float* __restrict__ bias,         // [NCT*16]
        void* __restrict__ out, int out_stride, int out_cols,
        const int* __restrict__ gflag, int out_mode, int n_nodes) {
    __shared__ u32x4 ldsW[NCT * 16 * 32];
    int tid = threadIdx.x;
    for (int c = tid; c < NCT * 16 * 32; c += 256) {
        int nrow = c >> 5, ch = c & 31;
        ldsW[(nrow << 5) | (ch ^ (nrow & 7))] = Wg[c];
    }
    __syncthreads();

    int wave = tid >> 6, lane = tid & 63;
    int quad = lane >> 4, sub = lane & 15;
    int mynode = blockIdx.x * 64 + wave * 16 + sub;
    int arow = (mynode < n_nodes) ? mynode : (n_nodes - 1);
    const unsigned short* ap = X + (size_t)arow * 256 + quad * 8;

    f32x4 acc[NCT];
#pragma unroll
    for (int ct = 0; ct < NCT; ++ct) acc[ct] = (f32x4){0,0,0,0};

    short8 av = *(const short8*)ap;
#pragma unroll
    for (int kt = 0; kt < 8; ++kt) {
        short8 av_next = av;
        if (kt < 7) av_next = *(const short8*)(ap + (kt + 1) * 32);
        int chunk = kt * 4 + quad;
#pragma unroll
        for (int ct = 0; ct < NCT; ++ct) {
            int ncol = ct * 16 + sub;
            union { u32x4 u; short8 s; } cv;
            cv.u = ldsW[(ncol << 5) | (chunk ^ (ncol & 7))];
            acc[ct] = __builtin_amdgcn_mfma_f32_16x16x32_bf16(cv.s, av, acc[ct], 0, 0, 0);
        }
        av = av_next;
    }

    int gb  = *gflag;
    int obf = (out_mode == 2) ? gb : out_mode;
    float ss = 0.0f;
#pragma unroll
    for (int ct = 0; ct < NCT; ++ct) {
        f32x4 b4 = *(const f32x4*)(bias + ct * 16 + quad * 4);
#pragma unroll
        for (int r = 0; r < 4; ++r) {
            float v = acc[ct][r] + b4[r];
            if (ACTNORM) { v = fmaxf(v, 0.0f); ss += v * v; }
            acc[ct][r] = v;
        }
    }
    float scale = 1.0f;
    if (ACTNORM) {
        ss += __shfl_xor(ss, 16, 64);
        ss += __shfl_xor(ss, 32, 64);
        scale = 1.0f / fmaxf(sqrtf(ss), 1e-12f);
    }
    if (mynode < n_nodes) {
#pragma unroll
        for (int ct = 0; ct < NCT; ++ct) {
            int c0 = ct * 16 + quad * 4;
            if (c0 + 4 <= out_cols) {
                float v0 = acc[ct][0] * scale, v1 = acc[ct][1] * scale;
                float v2 = acc[ct][2] * scale, v3 = acc[ct][3] * scale;
                if (obf) {
                    u16x4 o = { f2bf(v0), f2bf(v1), f2bf(v2), f2bf(v3) };
                    *(u16x4*)((unsigned short*)out + (size_t)mynode * out_stride + c0) = o;
                } else {
                    f32x4 o = { v0, v1, v2, v3 };
                    *(f32x4*)((float*)out + (size_t)mynode * out_stride + c0) = o;
                }
            }
        }
    }
}

// ---------------------------------------------------------------------------
extern "C" void kernel_launch(void* const* d_in, const int* in_sizes, int n_in,
                              void* d_out, int out_size, void* d_ws, size_t ws_size,
                              hipStream_t stream) {
    const void* feats = d_in[0];
    const int*  src   = (const int*)d_in[1];
    const int*  dst   = (const int*)d_in[2];

    char* ws = (char*)d_ws;
    const size_t NI = (size_t)N_NODES_C * sizeof(int);
    unsigned short* X0   = (unsigned short*)ws;                       // 51,200,000 B
    unsigned short* X1   = (unsigned short*)(ws + 51200000);          // 51,200,000 B
    unsigned short* Wt   = (unsigned short*)(ws + 102400000);         //    155,648 B
    float*          bcat = (float*)(ws + 102560000);                  //      1,216 B
    int*  deg       = (int*)(ws + 102564096);
    int*  row_start = (int*)(ws + 102964096);
    int*  cursor    = (int*)(ws + 103364096);
    int*  csr       = (int*)(ws + 103764096);                         //  6,400,000 B
    int*  blocksum  = (int*)(ws + 110164096);
    int*  gflag     = (int*)(ws + 110166144);

    detect_kernel<<<1, 64, 0, stream>>>(feats, gflag);

    // CSR build
    hipMemsetAsync(deg, 0, NI, stream);
    deg_kernel<<<(N_EDGES_C + 255) / 256, 256, 0, stream>>>(dst, deg, N_EDGES_C);
    scan1_kernel<<<N_BLKS, SCAN_B, 0, stream>>>(deg, blocksum);
    scan2_kernel<<<1, 64, 0, stream>>>(blocksum);
    scan3_kernel<<<N_BLKS, SCAN_B, 0, stream>>>(deg, blocksum, row_start, cursor);
    csr_fill_kernel<<<(N_EDGES_C + 255) / 256, 256, 0, stream>>>(src, dst, cursor, csr, N_EDGES_C);

    // weights -> Wt/bcat (transposed, concatenated, bf16)
    prep_weights<<<304, 256, 0, stream>>>(
        d_in[3], d_in[4], d_in[5], d_in[6],
        d_in[7], d_in[8], d_in[9], d_in[10],
        d_in[11], d_in[12], d_in[13], d_in[14], Wt, bcat, gflag);

    const int gblk = (N_NODES_C + 3) / 4;      // gather: 4 nodes/block
    const int mblk = (N_NODES_C + 63) / 64;    // gemm: 64 nodes/block

    // layer 0: feats -> X0 -> X1[:,0:128]
    gather_kernel<<<gblk, 256, 0, stream>>>(feats, 128, 2, 1, csr, row_start, deg, X0, gflag);
    mfma_gemm<8, true><<<mblk, 256, 0, stream>>>(
        X0, (const u32x4*)Wt, bcat, X1, 256, 128, gflag, 1, N_NODES_C);

    // layer 1: X1 -> X0[:,0:128]
    gather_kernel<<<gblk, 256, 0, stream>>>(X1, 256, 1, 0, csr, row_start, deg, X1, gflag);
    mfma_gemm<8, true><<<mblk, 256, 0, stream>>>(
        X1, (const u32x4*)(Wt + 128 * 256), bcat + 128, X0, 256, 128, gflag, 1, N_NODES_C);

    // layer 2: X0 -> d_out (40 cols, no act/norm, adaptive out dtype)
    gather_kernel<<<gblk, 256, 0, stream>>>(X0, 256, 1, 0, csr, row_start, deg, X0, gflag);
    mfma_gemm<3, false><<<mblk, 256, 0, stream>>>(
        X0, (const u32x4*)(Wt + 256 * 256), bcat + 256, d_out, 40, 40, gflag, 2, N_NODES_C);
}